// Round 1
// baseline (23.395 us; speedup 1.0000x reference)
//
#include <hip/hip_runtime.h>
#include <math.h>

// ContrastiveLossOptimized: N=16384, y_pred f32, y_true f32 (binary), epoch int.
// epoch >= 5 branch collapses to closed form:
//   Total = 2*N*sum(p^2) - 2*(sum p)^2 + 2*n0*n1,  p = sigmoid(y_pred)
// epoch < 5 branch: mean BCE-with-logits (stable form).
// Single-block reduction kernel; everything accumulated in double.

#define NTHREADS 1024

__global__ __launch_bounds__(NTHREADS)
void closs_reduce_kernel(const float* __restrict__ y_pred,
                         const float* __restrict__ y_true,
                         const int* __restrict__ epoch_p,
                         float* __restrict__ out,
                         int n) {
    const int tid = threadIdx.x;

    double s1 = 0.0;   // sum p
    double s2 = 0.0;   // sum p^2
    double sb = 0.0;   // sum bce terms
    int    n1 = 0;     // count of labels != 0

    const int nvec = n >> 2;  // float4 count
    const float4* yp4 = reinterpret_cast<const float4*>(y_pred);
    const float4* yt4 = reinterpret_cast<const float4*>(y_true);

    for (int idx = tid; idx < nvec; idx += NTHREADS) {
        float4 xp = yp4[idx];
        float4 xt = yt4[idx];
        float xs[4] = {xp.x, xp.y, xp.z, xp.w};
        float ts[4] = {xt.x, xt.y, xt.z, xt.w};
#pragma unroll
        for (int j = 0; j < 4; ++j) {
            float x = xs[j];
            float t = ts[j];
            float p = 1.0f / (1.0f + expf(-x));
            s1 += (double)p;
            s2 += (double)p * (double)p;
            n1 += (t != 0.0f) ? 1 : 0;
            float b = fmaxf(x, 0.0f) - x * t + log1pf(expf(-fabsf(x)));
            sb += (double)b;
        }
    }
    // scalar tail (n not divisible by 4)
    for (int i = (nvec << 2) + tid; i < n; i += NTHREADS) {
        float x = y_pred[i];
        float t = y_true[i];
        float p = 1.0f / (1.0f + expf(-x));
        s1 += (double)p;
        s2 += (double)p * (double)p;
        n1 += (t != 0.0f) ? 1 : 0;
        float b = fmaxf(x, 0.0f) - x * t + log1pf(expf(-fabsf(x)));
        sb += (double)b;
    }

    // ---- wave (64-lane) reduction ----
#pragma unroll
    for (int off = 32; off > 0; off >>= 1) {
        s1 += __shfl_down(s1, off);
        s2 += __shfl_down(s2, off);
        sb += __shfl_down(sb, off);
        n1 += __shfl_down(n1, off);
    }

    // ---- cross-wave via LDS ----
    constexpr int NWAVES = NTHREADS / 64;
    __shared__ double sh1[NWAVES], sh2[NWAVES], shb[NWAVES];
    __shared__ int    shn[NWAVES];
    const int lane = tid & 63;
    const int wave = tid >> 6;
    if (lane == 0) {
        sh1[wave] = s1;
        sh2[wave] = s2;
        shb[wave] = sb;
        shn[wave] = n1;
    }
    __syncthreads();

    if (tid == 0) {
        double t1 = 0.0, t2 = 0.0, tb = 0.0;
        long long tn = 0;
#pragma unroll
        for (int w = 0; w < NWAVES; ++w) {
            t1 += sh1[w];
            t2 += sh2[w];
            tb += shb[w];
            tn += shn[w];
        }
        const int epoch = *epoch_p;
        double result;
        if (epoch < 5) {
            result = tb / (double)n;
        } else {
            const double dn  = (double)n;
            const double n1d = (double)tn;
            const double n0d = dn - n1d;
            result = 2.0 * dn * t2 - 2.0 * t1 * t1 + 2.0 * n0d * n1d;
        }
        out[0] = (float)result;
    }
}

extern "C" void kernel_launch(void* const* d_in, const int* in_sizes, int n_in,
                              void* d_out, int out_size, void* d_ws, size_t ws_size,
                              hipStream_t stream) {
    const float* y_pred = (const float*)d_in[0];
    const float* y_true = (const float*)d_in[1];
    const int*   epoch  = (const int*)d_in[2];
    float* out = (float*)d_out;
    const int n = in_sizes[0];

    closs_reduce_kernel<<<1, NTHREADS, 0, stream>>>(y_pred, y_true, epoch, out, n);
}

// Round 2
// 9.650 us; speedup vs baseline: 2.4243x; 2.4243x over previous
//
#include <hip/hip_runtime.h>
#include <math.h>

// ContrastiveLossOptimized: N=16384, y_pred f32, y_true f32 (binary), epoch int.
//
// epoch >= 5 branch collapses to closed form (pairwise sum is O(N)):
//   Total = 2*N*sum(p^2) - 2*(sum p)^2 + 2*n0*n1,   p = sigmoid(y_pred)
//   (cross term Sum_diff d vanishes by (i,j)/(j,i) antisymmetry)
// epoch < 5 branch: mean BCE-with-logits (stable form) — cold path.
//
// Single block (problem is 128 KB; launch overhead dominates). epoch is a
// wave-uniform scalar load -> the branch costs nothing; only one path's
// VALU work executes. Hot path: float accumulation (threshold 3.2e6, float
// sum error propagates to <1e3), fast exp + rcp for sigmoid.

#define NT 1024
#define NWAVES (NT / 64)

__global__ __launch_bounds__(NT)
void closs_kernel(const float* __restrict__ yp, const float* __restrict__ yt,
                  const int* __restrict__ ep, float* __restrict__ out, int n) {
    const int tid = threadIdx.x;
    const int epoch = *ep;  // uniform -> s_load, uniform branch

    __shared__ float  shf[3][NWAVES];
    __shared__ double shd[NWAVES];

    if (epoch >= 5) {
        // ---- hot path: closed-form contrastive sum ----
        float s1 = 0.0f;  // sum p
        float s2 = 0.0f;  // sum p^2
        float s3 = 0.0f;  // count(t != 0)

        const int nvec = n >> 2;
        const float4* yp4 = reinterpret_cast<const float4*>(yp);
        const float4* yt4 = reinterpret_cast<const float4*>(yt);

        for (int i = tid; i < nvec; i += NT) {
            float4 a = yp4[i];
            float4 b = yt4[i];
            float xs[4] = {a.x, a.y, a.z, a.w};
            float ts[4] = {b.x, b.y, b.z, b.w};
#pragma unroll
            for (int j = 0; j < 4; ++j) {
                float e = __expf(-xs[j]);                       // native exp
                float p = __builtin_amdgcn_rcpf(1.0f + e);      // 1-instr rcp
                s1 += p;
                s2 = fmaf(p, p, s2);
                s3 += (ts[j] != 0.0f) ? 1.0f : 0.0f;
            }
        }
        for (int i = (nvec << 2) + tid; i < n; i += NT) {       // tail
            float e = __expf(-yp[i]);
            float p = __builtin_amdgcn_rcpf(1.0f + e);
            s1 += p;
            s2 = fmaf(p, p, s2);
            s3 += (yt[i] != 0.0f) ? 1.0f : 0.0f;
        }

#pragma unroll
        for (int off = 32; off; off >>= 1) {
            s1 += __shfl_down(s1, off);
            s2 += __shfl_down(s2, off);
            s3 += __shfl_down(s3, off);
        }
        const int lane = tid & 63, wave = tid >> 6;
        if (lane == 0) { shf[0][wave] = s1; shf[1][wave] = s2; shf[2][wave] = s3; }
        __syncthreads();

        if (tid == 0) {
            double t1 = 0.0, t2 = 0.0, t3 = 0.0;
#pragma unroll
            for (int w = 0; w < NWAVES; ++w) {
                t1 += (double)shf[0][w];
                t2 += (double)shf[1][w];
                t3 += (double)shf[2][w];
            }
            const double dn = (double)n;
            out[0] = (float)(2.0 * dn * t2 - 2.0 * t1 * t1 + 2.0 * (dn - t3) * t3);
        }
    } else {
        // ---- cold path: mean BCE-with-logits (precise) ----
        double sb = 0.0;
        for (int i = tid; i < n; i += NT) {
            float x = yp[i], t = yt[i];
            sb += (double)(fmaxf(x, 0.0f) - x * t + log1pf(expf(-fabsf(x))));
        }
#pragma unroll
        for (int off = 32; off; off >>= 1) sb += __shfl_down(sb, off);
        const int lane = tid & 63, wave = tid >> 6;
        if (lane == 0) shd[wave] = sb;
        __syncthreads();

        if (tid == 0) {
            double tb = 0.0;
#pragma unroll
            for (int w = 0; w < NWAVES; ++w) tb += shd[w];
            out[0] = (float)(tb / (double)n);
        }
    }
}

extern "C" void kernel_launch(void* const* d_in, const int* in_sizes, int n_in,
                              void* d_out, int out_size, void* d_ws, size_t ws_size,
                              hipStream_t stream) {
    const float* y_pred = (const float*)d_in[0];
    const float* y_true = (const float*)d_in[1];
    const int*   epoch  = (const int*)d_in[2];
    float* out = (float*)d_out;
    const int n = in_sizes[0];

    closs_kernel<<<1, NT, 0, stream>>>(y_pred, y_true, epoch, out, n);
}

// Round 3
// 9.590 us; speedup vs baseline: 2.4396x; 1.0063x over previous
//
#include <hip/hip_runtime.h>
#include <math.h>

// ContrastiveLossOptimized: N=16384, y_pred f32, y_true f32 (binary), epoch int.
//
// epoch >= 5 branch collapses to closed form (pairwise sum is O(N)):
//   Total = 2*N*sum(p^2) - 2*(sum p)^2 + 2*n0*n1,   p = sigmoid(y_pred)
// epoch < 5: mean BCE-with-logits (stable form) — cold path.
//
// Single block; problem is 128 KB so dispatch overhead dominates. The n==16384
// fast path issues all 8 global_load_dwordx4 per thread up-front -> one memory
// round-trip on the critical path instead of 4 (runtime-trip-count grid-stride
// loop can't be fully unrolled by the compiler).

#define NT 1024
#define NWAVES (NT / 64)

__device__ __forceinline__ void acc4(float4 a, float4 b,
                                     float& s1, float& s2, float& s3) {
    float xs[4] = {a.x, a.y, a.z, a.w};
    float ts[4] = {b.x, b.y, b.z, b.w};
#pragma unroll
    for (int j = 0; j < 4; ++j) {
        float e = __expf(-xs[j]);                  // v_exp_f32 (TRANS pipe)
        float p = __builtin_amdgcn_rcpf(1.0f + e); // 1-instr rcp
        s1 += p;
        s2 = fmaf(p, p, s2);
        s3 += (ts[j] != 0.0f) ? 1.0f : 0.0f;
    }
}

__global__ __launch_bounds__(NT)
void closs_kernel(const float* __restrict__ yp, const float* __restrict__ yt,
                  const int* __restrict__ ep, float* __restrict__ out, int n) {
    const int tid = threadIdx.x;
    const int epoch = *ep;  // wave-uniform scalar -> uniform branch

    __shared__ float  shf[3][NWAVES];
    __shared__ double shd[NWAVES];
    const int lane = tid & 63, wave = tid >> 6;

    if (epoch >= 5) {
        float s1 = 0.0f, s2 = 0.0f, s3 = 0.0f;
        const float4* yp4 = reinterpret_cast<const float4*>(yp);
        const float4* yt4 = reinterpret_cast<const float4*>(yt);

        if (n == NT * 16) {
            // fast path: 4 float4 pairs/thread, all loads in flight at once
            float4 a0 = yp4[tid];
            float4 a1 = yp4[tid + NT];
            float4 a2 = yp4[tid + 2 * NT];
            float4 a3 = yp4[tid + 3 * NT];
            float4 b0 = yt4[tid];
            float4 b1 = yt4[tid + NT];
            float4 b2 = yt4[tid + 2 * NT];
            float4 b3 = yt4[tid + 3 * NT];
            acc4(a0, b0, s1, s2, s3);
            acc4(a1, b1, s1, s2, s3);
            acc4(a2, b2, s1, s2, s3);
            acc4(a3, b3, s1, s2, s3);
        } else {
            const int nvec = n >> 2;
            for (int i = tid; i < nvec; i += NT)
                acc4(yp4[i], yt4[i], s1, s2, s3);
            for (int i = (nvec << 2) + tid; i < n; i += NT) {
                float e = __expf(-yp[i]);
                float p = __builtin_amdgcn_rcpf(1.0f + e);
                s1 += p;
                s2 = fmaf(p, p, s2);
                s3 += (yt[i] != 0.0f) ? 1.0f : 0.0f;
            }
        }

#pragma unroll
        for (int off = 32; off; off >>= 1) {
            s1 += __shfl_down(s1, off);
            s2 += __shfl_down(s2, off);
            s3 += __shfl_down(s3, off);
        }
        if (lane == 0) { shf[0][wave] = s1; shf[1][wave] = s2; shf[2][wave] = s3; }
        __syncthreads();

        // first wave reduces the 16 per-wave partials
        if (wave == 0) {
            float t1 = (lane < NWAVES) ? shf[0][lane] : 0.0f;
            float t2 = (lane < NWAVES) ? shf[1][lane] : 0.0f;
            float t3 = (lane < NWAVES) ? shf[2][lane] : 0.0f;
#pragma unroll
            for (int off = 8; off; off >>= 1) {
                t1 += __shfl_down(t1, off);
                t2 += __shfl_down(t2, off);
                t3 += __shfl_down(t3, off);
            }
            if (lane == 0) {
                const double dn = (double)n;
                const double d1 = (double)t1, d2 = (double)t2, d3 = (double)t3;
                out[0] = (float)(2.0 * dn * d2 - 2.0 * d1 * d1
                                 + 2.0 * (dn - d3) * d3);
            }
        }
    } else {
        // ---- cold path: mean BCE-with-logits (precise) ----
        double sb = 0.0;
        for (int i = tid; i < n; i += NT) {
            float x = yp[i], t = yt[i];
            sb += (double)(fmaxf(x, 0.0f) - x * t + log1pf(expf(-fabsf(x))));
        }
#pragma unroll
        for (int off = 32; off; off >>= 1) sb += __shfl_down(sb, off);
        if (lane == 0) shd[wave] = sb;
        __syncthreads();
        if (tid == 0) {
            double tb = 0.0;
#pragma unroll
            for (int w = 0; w < NWAVES; ++w) tb += shd[w];
            out[0] = (float)(tb / (double)n);
        }
    }
}

extern "C" void kernel_launch(void* const* d_in, const int* in_sizes, int n_in,
                              void* d_out, int out_size, void* d_ws, size_t ws_size,
                              hipStream_t stream) {
    const float* y_pred = (const float*)d_in[0];
    const float* y_true = (const float*)d_in[1];
    const int*   epoch  = (const int*)d_in[2];
    float* out = (float*)d_out;
    const int n = in_sizes[0];

    closs_kernel<<<1, NT, 0, stream>>>(y_pred, y_true, epoch, out, n);
}